// Round 2
// baseline (870.373 us; speedup 1.0000x reference)
//
#include <hip/hip_runtime.h>
#include <stdint.h>

#define BM 128
#define BN 128
#define BK 32
#define DIMD 512
#define NROWS 65536
#define QOFF 1
#define PERPOFF 33554433
#define PROBSOFF 33554434
#define NELEM 33554432

typedef __attribute__((ext_vector_type(8))) short bf16x8;
typedef __attribute__((ext_vector_type(4))) short s16x4;
typedef __attribute__((ext_vector_type(4))) float f32x4;

typedef const __attribute__((address_space(1))) void* gas_ptr;
typedef __attribute__((address_space(3))) void* las_ptr;

__device__ __forceinline__ short f2bf(float x){
  uint32_t u = __builtin_bit_cast(uint32_t, x);
  uint32_t r = (u + 0x7fffu + ((u >> 16) & 1u)) >> 16;
  return (short)(uint16_t)r;
}
__device__ __forceinline__ float bf2f(short h){
  return __builtin_bit_cast(float, ((uint32_t)(uint16_t)h) << 16);
}

// ---------------- helpers for k_gemm_mean (unchanged structure) ----------------
__device__ __forceinline__ void stage_bf16(const short* __restrict__ g, int row0, int ld, int k0,
                                           short* lds){
  int tid = threadIdx.x;
#pragma unroll
  for (int i = 0; i < 2; ++i){
    int t = tid + i * 256;
    int row = t >> 2, c = t & 3;
    const short* src = g + (long)(row0 + row) * ld + k0 + c * 8;
    __builtin_amdgcn_global_load_lds((gas_ptr)src, (las_ptr)(lds + t * 8), 16, 0, 0);
  }
}

__device__ __forceinline__ void stage_f32_split(const float* __restrict__ g, int row0, int ld, int k0,
                                                short* hi, short* lo){
  int tid = threadIdx.x;
#pragma unroll
  for (int i = 0; i < 4; ++i){
    int t = tid + i * 256;
    int row = t >> 3, c = t & 7;
    const float4 v = *(const float4*)(g + (long)(row0 + row) * ld + k0 + c * 4);
    short h0 = f2bf(v.x), h1 = f2bf(v.y), h2 = f2bf(v.z), h3 = f2bf(v.w);
    s16x4 hv; hv[0] = h0; hv[1] = h1; hv[2] = h2; hv[3] = h3;
    s16x4 lv;
    lv[0] = f2bf(v.x - bf2f(h0)); lv[1] = f2bf(v.y - bf2f(h1));
    lv[2] = f2bf(v.z - bf2f(h2)); lv[3] = f2bf(v.w - bf2f(h3));
    *(s16x4*)(hi + row * BK + c * 4) = hv;
    *(s16x4*)(lo + row * BK + c * 4) = lv;
  }
}

__device__ __forceinline__ bf16x8 frag(const short* lds, int r, int q){
  return *(const bf16x8*)(lds + r * BK + q * 8);
}

// ---------------- weight conversion ----------------
// Fragged layout for weight tensor W'[row 512][k 512]:
//   elem offset = (k>>5)*16384 + row*32 + (k&31)
// so a B-fragment load (lane q,m reads row tile+m, k chunk q*8) is a wave-contiguous 1KB read.
__global__ __launch_bounds__(256) void k_convert_w(
    const float* __restrict__ meanW, const float* __restrict__ lvW, const float* __restrict__ emb,
    short* __restrict__ MWThi, short* __restrict__ MWTlo,
    short* __restrict__ VWh, short* __restrict__ VWl,
    short* __restrict__ E, short* __restrict__ ET, float* __restrict__ enorm)
{
  int b = blockIdx.x;      // b = input-dim index for MW/VW rows; codebook row for emb
  int tid = threadIdx.x;
  float esum = 0.f;
  for (int j = tid; j < 512; j += 256){
    // mean weights: plain B^T layout (consumed by k_gemm_mean's LDS staging)
    float w = meanW[b * 512 + j];
    short h = f2bf(w); short l = f2bf(w - bf2f(h));
    MWThi[j * 512 + b] = h; MWTlo[j * 512 + b] = l;
    // logvar weights: fragged, row=j (code), k=b (input dim)
    float v = lvW[b * 512 + j];
    h = f2bf(v); l = f2bf(v - bf2f(h));
    long offW = ((long)(b >> 5) << 14) + j * 32 + (b & 31);
    VWh[offW] = h; VWl[offW] = l;
    // embedding: E' row=code(b), k=d(j);  ET' row=d(j), k=code(b)
    float e = emb[b * 512 + j];
    short eh = f2bf(e);
    E[((long)(j >> 5) << 14) + b * 32 + (j & 31)] = eh;
    ET[((long)(b >> 5) << 14) + j * 32 + (b & 31)] = eh;
    esum += e * e;
  }
  for (int o = 32; o >= 1; o >>= 1) esum += __shfl_xor(esum, o);
  __shared__ float red[4];
  if ((tid & 63) == 0) red[tid >> 6] = esum;
  __syncthreads();
  if (tid == 0) enorm[b] = red[0] + red[1] + red[2] + red[3];
}

// ---------------- G1: x = inputs @ mean_W + mean_b ----------------
// Unchanged GEMM; epilogue now writes X in fragged layout:
//   off = (row>>6)*32768 + (col>>5)*2048 + (row&63)*32 + (col&31)
__global__ __launch_bounds__(256, 2) void k_gemm_mean(
    const float* __restrict__ inp, const short* __restrict__ Bhi, const short* __restrict__ Blo,
    const float* __restrict__ bias, short* __restrict__ Xhi, short* __restrict__ Xlo,
    float* __restrict__ xnorm)
{
  __shared__ short Ah[BM * BK], Al[BM * BK], Bh[BN * BK], Bl[BN * BK];
  int tid = threadIdx.x;
  int n0 = blockIdx.x * BM, c0 = blockIdx.y * BN;
  int lane = tid & 63, wid = tid >> 6;
  int wm = wid >> 1, wn = wid & 1;
  int q = lane >> 4, m = lane & 15;
  f32x4 acc[4][4];
#pragma unroll
  for (int i = 0; i < 4; i++)
#pragma unroll
    for (int j = 0; j < 4; j++)
#pragma unroll
      for (int r = 0; r < 4; r++) acc[i][j][r] = 0.f;

  for (int k0 = 0; k0 < DIMD; k0 += BK){
    __syncthreads();
    stage_f32_split(inp, n0, DIMD, k0, Ah, Al);
    stage_bf16(Bhi, c0, DIMD, k0, Bh);
    stage_bf16(Blo, c0, DIMD, k0, Bl);
    __syncthreads();
    bf16x8 ah[4], al[4], bh[4], bl[4];
#pragma unroll
    for (int i = 0; i < 4; i++){
      ah[i] = frag(Ah, wm * 64 + i * 16 + m, q);
      al[i] = frag(Al, wm * 64 + i * 16 + m, q);
      bh[i] = frag(Bh, wn * 64 + i * 16 + m, q);
      bl[i] = frag(Bl, wn * 64 + i * 16 + m, q);
    }
#pragma unroll
    for (int i = 0; i < 4; i++)
#pragma unroll
      for (int j = 0; j < 4; j++){
        acc[i][j] = __builtin_amdgcn_mfma_f32_16x16x32_bf16(ah[i], bh[j], acc[i][j], 0, 0, 0);
        acc[i][j] = __builtin_amdgcn_mfma_f32_16x16x32_bf16(ah[i], bl[j], acc[i][j], 0, 0, 0);
        acc[i][j] = __builtin_amdgcn_mfma_f32_16x16x32_bf16(al[i], bh[j], acc[i][j], 0, 0, 0);
      }
  }
#pragma unroll
  for (int i = 0; i < 4; i++){
#pragma unroll
    for (int r = 0; r < 4; r++){
      int row = n0 + wm * 64 + i * 16 + q * 4 + r;
      float xn = 0.f;
#pragma unroll
      for (int j = 0; j < 4; j++){
        int col = c0 + wn * 64 + j * 16 + m;
        float x = acc[i][j][r] + bias[col];
        short h = f2bf(x);
        short l = f2bf(x - bf2f(h));
        long off = ((long)(row >> 6) << 15) + ((long)(col >> 5) << 11) + (row & 63) * 32 + (col & 31);
        Xhi[off] = h;
        Xlo[off] = l;
        xn += x * x;
      }
      xn += __shfl_xor(xn, 1); xn += __shfl_xor(xn, 2);
      xn += __shfl_xor(xn, 4); xn += __shfl_xor(xn, 8);
      if (m == 0) atomicAdd(&xnorm[row], xn);
    }
  }
}

// ---------------- fused: zlv + S + softmax + quant + loss ----------------
// 1024 blocks x 1024 threads (16 waves). Block owns 64 rows x all 512 codes.
// Wave wid owns 64 rows x 32 cols (c0 = wid*32). No LDS staging for GEMM operands:
// A/B fragments load directly from fragged global (coalesced 1KB/wave); no K-loop barriers.
__global__ __launch_bounds__(1024) void k_fused(
    const short* __restrict__ Xh, const short* __restrict__ Xl,
    const short* __restrict__ Vh, const short* __restrict__ Vl,
    const short* __restrict__ Eb, const short* __restrict__ Et,
    const float* __restrict__ lvb, const float* __restrict__ xnorm,
    const float* __restrict__ enorm, const float* __restrict__ inp,
    float* __restrict__ probs, float* __restrict__ qout,
    float* __restrict__ Pacc, float* __restrict__ lossacc)
{
  __shared__ short P[64 * 512];   // 64KB swizzled probs bf16
  __shared__ float rrM[16][64];   // per-wave row-max partials
  __shared__ float rrS[16][64];   // per-wave row-sum partials

  const int tid = threadIdx.x;
  const int n0 = blockIdx.x * 64;
  const int lane = tid & 63, wid = tid >> 6;
  const int q = lane >> 4, m = lane & 15;
  const int c0 = wid * 32;

  const short* Xhb = Xh + (long)blockIdx.x * 32768;
  const short* Xlb = Xl + (long)blockIdx.x * 32768;

  f32x4 accZ[4][2];
#pragma unroll
  for (int i = 0; i < 4; i++)
#pragma unroll
    for (int j = 0; j < 2; j++)
#pragma unroll
      for (int r = 0; r < 4; r++) accZ[i][j][r] = 0.f;

  // ---- phase Z: zlv = x @ logvar_W (split bf16, 3 terms) ----
  for (int ks = 0; ks < 16; ++ks){
    const short* xh = Xhb + ks * 2048;
    const short* xl = Xlb + ks * 2048;
    const short* vh = Vh + ks * 16384;
    const short* vl = Vl + ks * 16384;
    bf16x8 ah[4], al[4], bh[2], bl[2];
#pragma unroll
    for (int i = 0; i < 4; i++){
      ah[i] = *(const bf16x8*)(xh + i * 512 + m * 32 + q * 8);
      al[i] = *(const bf16x8*)(xl + i * 512 + m * 32 + q * 8);
    }
#pragma unroll
    for (int j = 0; j < 2; j++){
      bh[j] = *(const bf16x8*)(vh + (c0 + j * 16 + m) * 32 + q * 8);
      bl[j] = *(const bf16x8*)(vl + (c0 + j * 16 + m) * 32 + q * 8);
    }
#pragma unroll
    for (int j = 0; j < 2; j++)
#pragma unroll
      for (int i = 0; i < 4; i++){
        accZ[i][j] = __builtin_amdgcn_mfma_f32_16x16x32_bf16(ah[i], bh[j], accZ[i][j], 0, 0, 0);
        accZ[i][j] = __builtin_amdgcn_mfma_f32_16x16x32_bf16(ah[i], bl[j], accZ[i][j], 0, 0, 0);
        accZ[i][j] = __builtin_amdgcn_mfma_f32_16x16x32_bf16(al[i], bh[j], accZ[i][j], 0, 0, 0);
      }
  }

  // ---- phase S: S = x_hi @ E^T (plain bf16) ----
  f32x4 accS[4][2];
#pragma unroll
  for (int i = 0; i < 4; i++)
#pragma unroll
    for (int j = 0; j < 2; j++)
#pragma unroll
      for (int r = 0; r < 4; r++) accS[i][j][r] = 0.f;
  for (int ks = 0; ks < 16; ++ks){
    const short* xh = Xhb + ks * 2048;
    const short* eb = Eb + ks * 16384;
    bf16x8 ah[4], be[2];
#pragma unroll
    for (int i = 0; i < 4; i++) ah[i] = *(const bf16x8*)(xh + i * 512 + m * 32 + q * 8);
#pragma unroll
    for (int j = 0; j < 2; j++) be[j] = *(const bf16x8*)(eb + (c0 + j * 16 + m) * 32 + q * 8);
#pragma unroll
    for (int j = 0; j < 2; j++)
#pragma unroll
      for (int i = 0; i < 4; i++)
        accS[i][j] = __builtin_amdgcn_mfma_f32_16x16x32_bf16(ah[i], be[j], accS[i][j], 0, 0, 0);
  }

  // ---- logits (in-register) ----
  float lvbv[2], env[2];
#pragma unroll
  for (int j = 0; j < 2; j++){
    int col = c0 + j * 16 + m;
    lvbv[j] = lvb[col];
    env[j] = enorm[col];
  }
  float xnv[4][4];
#pragma unroll
  for (int i = 0; i < 4; i++)
#pragma unroll
    for (int r = 0; r < 4; r++) xnv[i][r] = xnorm[n0 + i * 16 + q * 4 + r];

  const float inv800 = 0.5f / 400.0f;
#pragma unroll
  for (int i = 0; i < 4; i++)
#pragma unroll
    for (int j = 0; j < 2; j++)
#pragma unroll
      for (int r = 0; r < 4; r++){
        float z = accZ[i][j][r] + lvbv[j];
        float s = accS[i][j][r];
        float sm = __expf(-2.f * z);
        accS[i][j][r] = z - inv800 * (xnv[i][r] + env[j] - 2.f * s) * sm;
      }

  // ---- softmax: row max (wave partial -> LDS -> redundant wave reduce -> shfl bcast) ----
#pragma unroll
  for (int i = 0; i < 4; i++)
#pragma unroll
    for (int r = 0; r < 4; r++){
      float v = fmaxf(accS[i][0][r], accS[i][1][r]);
      v = fmaxf(v, __shfl_xor(v, 1));
      v = fmaxf(v, __shfl_xor(v, 2));
      v = fmaxf(v, __shfl_xor(v, 4));
      v = fmaxf(v, __shfl_xor(v, 8));
      if (m == 0) rrM[wid][i * 16 + q * 4 + r] = v;
    }
  __syncthreads();
  float rmax;
  {
    float v = rrM[0][lane];
#pragma unroll
    for (int w = 1; w < 16; w++) v = fmaxf(v, rrM[w][lane]);
    rmax = v;    // lane l holds max of row l
  }
  float mxf[4][4];
#pragma unroll
  for (int i = 0; i < 4; i++)
#pragma unroll
    for (int r = 0; r < 4; r++) mxf[i][r] = __shfl(rmax, i * 16 + q * 4 + r);

  // ---- softmax: exp + row sum ----
#pragma unroll
  for (int i = 0; i < 4; i++)
#pragma unroll
    for (int r = 0; r < 4; r++){
      float sacc = 0.f;
#pragma unroll
      for (int j = 0; j < 2; j++){
        float p = __expf(accS[i][j][r] - mxf[i][r]);
        accS[i][j][r] = p;
        sacc += p;
      }
      sacc += __shfl_xor(sacc, 1);
      sacc += __shfl_xor(sacc, 2);
      sacc += __shfl_xor(sacc, 4);
      sacc += __shfl_xor(sacc, 8);
      if (m == 0) rrS[wid][i * 16 + q * 4 + r] = sacc;
    }
  __syncthreads();
  float rsum;
  {
    float v = 0.f;
#pragma unroll
    for (int w = 0; w < 16; w++) v += rrS[w][lane];
    rsum = v;    // lane l holds sum of row l
  }
  float smr[4][4];
#pragma unroll
  for (int i = 0; i < 4; i++)
#pragma unroll
    for (int r = 0; r < 4; r++) smr[i][r] = __shfl(rsum, i * 16 + q * 4 + r);

  // ---- probs out (fp32 global), probs bf16 -> swizzled LDS, Pacc ----
  float pj[2];
  pj[0] = 0.f; pj[1] = 0.f;
#pragma unroll
  for (int i = 0; i < 4; i++)
#pragma unroll
    for (int r = 0; r < 4; r++){
      int rowl = i * 16 + q * 4 + r;
      long rowg = n0 + rowl;
      float inv = 1.0f / smr[i][r];
#pragma unroll
      for (int j = 0; j < 2; j++){
        int col = c0 + j * 16 + m;
        float qv = accS[i][j][r] * inv;
        probs[rowg * 512 + col] = qv;
        pj[j] += qv;
        int cg = col >> 3;
        P[rowl * 512 + (((cg ^ (rowl & 7)) << 3) | (col & 7))] = f2bf(qv);
      }
    }
#pragma unroll
  for (int j = 0; j < 2; j++){
    pj[j] += __shfl_xor(pj[j], 16);
    pj[j] += __shfl_xor(pj[j], 32);
  }
  if (lane < 16){
#pragma unroll
    for (int j = 0; j < 2; j++) atomicAdd(&Pacc[c0 + j * 16 + m], pj[j]);
  }
  __syncthreads();   // P visible to all waves

  // ---- quant: q = probs_bf16 @ embedding (A from LDS, B from fragged global) ----
  f32x4 accQ[4][2];
#pragma unroll
  for (int i = 0; i < 4; i++)
#pragma unroll
    for (int j = 0; j < 2; j++)
#pragma unroll
      for (int r = 0; r < 4; r++) accQ[i][j][r] = 0.f;
  for (int ks = 0; ks < 16; ++ks){
    int k0 = ks * 32;
    const short* et = Et + ks * 16384;
    bf16x8 pa[4], bq[2];
#pragma unroll
    for (int i = 0; i < 4; i++){
      int rowl = i * 16 + m;
      int cg = (k0 >> 3) + q;
      pa[i] = *(const bf16x8*)(P + rowl * 512 + ((cg ^ (rowl & 7)) << 3));
    }
#pragma unroll
    for (int j = 0; j < 2; j++) bq[j] = *(const bf16x8*)(et + (c0 + j * 16 + m) * 32 + q * 8);
#pragma unroll
    for (int j = 0; j < 2; j++)
#pragma unroll
      for (int i = 0; i < 4; i++)
        accQ[i][j] = __builtin_amdgcn_mfma_f32_16x16x32_bf16(pa[i], bq[j], accQ[i][j], 0, 0, 0);
  }

  // ---- quant epilogue: write qout, accumulate loss ----
  float lsum = 0.f;
#pragma unroll
  for (int i = 0; i < 4; i++)
#pragma unroll
    for (int r = 0; r < 4; r++){
      long rowg = n0 + i * 16 + q * 4 + r;
#pragma unroll
      for (int j = 0; j < 2; j++){
        int col = c0 + j * 16 + m;
        float qv = accQ[i][j][r];
        long idx = rowg * 512 + col;
        qout[idx] = qv;
        float d = qv - inp[idx];
        lsum += d * d;
      }
    }
  lsum += __shfl_xor(lsum, 32);
  lsum += __shfl_xor(lsum, 16);
  lsum += __shfl_xor(lsum, 8);
  lsum += __shfl_xor(lsum, 4);
  lsum += __shfl_xor(lsum, 2);
  lsum += __shfl_xor(lsum, 1);
  if (lane == 0) rrM[0][wid] = lsum;
  __syncthreads();
  if (tid == 0){
    float t = 0.f;
#pragma unroll
    for (int w = 0; w < 16; w++) t += rrM[0][w];
    atomicAdd(lossacc, t);
  }
}

// ---------------- G5: loss + perplexity ----------------
__global__ __launch_bounds__(256) void k_final(
    const float* __restrict__ Pacc, const float* __restrict__ lossacc, float* __restrict__ out)
{
  int tid = threadIdx.x;
  float h = 0.f;
  for (int k = tid; k < 512; k += 256){
    float a = Pacc[k] * (1.0f / 65536.0f);
    h += a * __logf(a + 1e-10f);
  }
  for (int o = 32; o >= 1; o >>= 1) h += __shfl_xor(h, o);
  __shared__ float red[4];
  if ((tid & 63) == 0) red[tid >> 6] = h;
  __syncthreads();
  if (tid == 0){
    float H = red[0] + red[1] + red[2] + red[3];
    out[0] = 1.25f * lossacc[0] * (1.0f / (float)NELEM);
    out[PERPOFF] = __expf(-H);
  }
}

extern "C" void kernel_launch(void* const* d_in, const int* in_sizes, int n_in,
                              void* d_out, int out_size, void* d_ws, size_t ws_size,
                              hipStream_t stream)
{
  const float* inp   = (const float*)d_in[0];
  const float* meanW = (const float*)d_in[1];
  const float* meanb = (const float*)d_in[2];
  const float* lvW   = (const float*)d_in[3];
  const float* lvb   = (const float*)d_in[4];
  const float* emb   = (const float*)d_in[5];
  float* out = (float*)d_out;

  // workspace carve
  char* w = (char*)d_ws;
  short* Xhi = (short*)w;   w += (size_t)NROWS * DIMD * 2;      // 67.1 MB (fragged)
  short* Xlo = (short*)w;   w += (size_t)NROWS * DIMD * 2;      // 67.1 MB (fragged)
  short* MWThi = (short*)w; w += 512 * 512 * 2;                 // plain B^T
  short* MWTlo = (short*)w; w += 512 * 512 * 2;                 // plain B^T
  short* VWh   = (short*)w; w += 512 * 512 * 2;                 // fragged
  short* VWl   = (short*)w; w += 512 * 512 * 2;                 // fragged
  short* E     = (short*)w; w += 512 * 512 * 2;                 // fragged
  short* ET    = (short*)w; w += 512 * 512 * 2;                 // fragged
  float* enorm = (float*)w; w += 512 * 4;
  float* stats = (float*)w;                    // xnorm[65536] + Pacc[512] + lossacc
  float* xnorm   = stats;
  float* Pacc    = stats + NROWS;
  float* lossacc = stats + NROWS + 512;

  hipMemsetAsync(stats, 0, (size_t)(NROWS + 512 + 16) * 4, stream);

  k_convert_w<<<512, 256, 0, stream>>>(meanW, lvW, emb, MWThi, MWTlo, VWh, VWl, E, ET, enorm);
  k_gemm_mean<<<dim3(512, 4), 256, 0, stream>>>(inp, MWThi, MWTlo, meanb, Xhi, Xlo, xnorm);
  k_fused<<<1024, 1024, 0, stream>>>(Xhi, Xlo, VWh, VWl, E, ET, lvb, xnorm, enorm, inp,
                                     out + PROBSOFF, out + QOFF, Pacc, lossacc);
  k_final<<<1, 256, 0, stream>>>(Pacc, lossacc, out);
}

// Round 3
// 699.720 us; speedup vs baseline: 1.2439x; 1.2439x over previous
//
#include <hip/hip_runtime.h>
#include <stdint.h>

#define DIMD 512
#define NROWS 65536
#define QOFF 1
#define PERPOFF 33554433
#define PROBSOFF 33554434
#define NELEM 33554432

typedef __attribute__((ext_vector_type(8))) short bf16x8;
typedef __attribute__((ext_vector_type(4))) short s16x4;
typedef __attribute__((ext_vector_type(4))) float f32x4;

__device__ __forceinline__ short f2bf(float x){
  uint32_t u = __builtin_bit_cast(uint32_t, x);
  uint32_t r = (u + 0x7fffu + ((u >> 16) & 1u)) >> 16;
  return (short)(uint16_t)r;
}
__device__ __forceinline__ float bf2f(short h){
  return __builtin_bit_cast(float, ((uint32_t)(uint16_t)h) << 16);
}

// A/P LDS tile layout: [row 64][k 512] bf16, 8-short chunks XOR-swizzled:
//   addr(row, k) = row*512 + (((k>>3) ^ (row&7))<<3) + (k&7)
// Frag read (lane q,m; row=i*16+m; k-chunk kc=ks*4+q) is conflict-free:
// 8 chunks x 4 banks = 32 banks, 8 lanes/bank-group = exact LDS BW minimum.
__device__ __forceinline__ int aoff(int row, int kc){
  return row * 512 + ((kc ^ (row & 7)) << 3);
}

// ---------------- weight conversion ----------------
// Fragged weight layout W'[row 512][k 512]: off = (k>>5)*16384 + row*32 + (k&31)
// so a B-frag load (lane q,m: row tile+m, k chunk q*8) is a wave-contiguous 1KB read.
__global__ __launch_bounds__(256) void k_convert_w(
    const float* __restrict__ meanW, const float* __restrict__ lvW, const float* __restrict__ emb,
    short* __restrict__ MWfh, short* __restrict__ MWfl,
    short* __restrict__ VWh, short* __restrict__ VWl,
    short* __restrict__ Eb, short* __restrict__ Et, float* __restrict__ enorm)
{
  int b = blockIdx.x;      // b = input-dim index for MW/VW; codebook row for emb
  int tid = threadIdx.x;
  float esum = 0.f;
  for (int j = tid; j < 512; j += 256){
    long offB = ((long)(b >> 5) << 14) + j * 32 + (b & 31);   // row=j, k=b
    float w = meanW[b * 512 + j];            // X = inp @ meanW: B row = out-d (j), k = in-d (b)
    short h = f2bf(w); short l = f2bf(w - bf2f(h));
    MWfh[offB] = h; MWfl[offB] = l;
    float v = lvW[b * 512 + j];              // zlv: B row = code (j), k = in-d (b)
    h = f2bf(v); l = f2bf(v - bf2f(h));
    VWh[offB] = h; VWl[offB] = l;
    float e = emb[b * 512 + j];
    short eh = f2bf(e);
    Eb[((long)(j >> 5) << 14) + b * 32 + (j & 31)] = eh;   // S: B row = code (b), k = d (j)
    Et[offB] = eh;                                          // quant: B row = d (j), k = code (b)
    esum += e * e;
  }
  for (int o = 32; o >= 1; o >>= 1) esum += __shfl_xor(esum, o);
  __shared__ float red[4];
  if ((tid & 63) == 0) red[tid >> 6] = esum;
  __syncthreads();
  if (tid == 0) enorm[b] = red[0] + red[1] + red[2] + red[3];
}

// ---------------- mega-fused: mean + zlv + S + softmax + quant + loss ----------------
// 1024 blocks x 1024 threads (16 waves, 4/SIMD). Block owns 64 rows x all 512 cols.
// Wave wid: all 64 rows x 32 cols (c0 = wid*32). X lives only in LDS (written in place
// over the inp split). No per-K-step barriers; B-frags from fragged global with 1-deep
// register prefetch; A-frags from swizzled LDS.
__global__ __launch_bounds__(1024, 1) void k_fused(
    const float* __restrict__ inp,
    const short* __restrict__ MWfh, const short* __restrict__ MWfl,
    const short* __restrict__ VWh, const short* __restrict__ VWl,
    const short* __restrict__ Eb, const short* __restrict__ Et,
    const float* __restrict__ meanb, const float* __restrict__ lvb,
    const float* __restrict__ enorm,
    float* __restrict__ probs, float* __restrict__ qout,
    float* __restrict__ Pacc, float* __restrict__ lossacc)
{
  __shared__ short Ih[64 * 512];   // 64KB: inp-hi, then X-hi, then P (probs bf16)
  __shared__ short Il[64 * 512];   // 64KB: inp-lo, then X-lo
  __shared__ float rrM[16][64];    // cross-wave reduce (max / loss)
  __shared__ float rrS[16][64];    // cross-wave reduce (xnorm / sum)

  const int tid = threadIdx.x;
  const int n0 = blockIdx.x * 64;
  const int lane = tid & 63, wid = tid >> 6;
  const int q = lane >> 4, m = lane & 15;
  const int c0 = wid * 32;

  // per-wave invariant B offsets (within a k-slab): row = c0 + j*16 + m, chunk q
  int boff0 = (c0 + m) * 32 + q * 8;
  int boff1 = (c0 + 16 + m) * 32 + q * 8;

  // ---- phase 0: inp -> hi/lo bf16 split into LDS (each thread distinct data) ----
  {
    const float* inpb = inp + (long)n0 * 512;
#pragma unroll
    for (int it = 0; it < 8; ++it){
      int fid = tid + it * 1024;          // float4 id; 8192 total = 64 rows x 128
      int row = fid >> 7, f = fid & 127;
      const float4 v = *(const float4*)(inpb + (long)fid * 4);
      short h0 = f2bf(v.x), h1 = f2bf(v.y), h2 = f2bf(v.z), h3 = f2bf(v.w);
      s16x4 hv; hv[0] = h0; hv[1] = h1; hv[2] = h2; hv[3] = h3;
      s16x4 lv;
      lv[0] = f2bf(v.x - bf2f(h0)); lv[1] = f2bf(v.y - bf2f(h1));
      lv[2] = f2bf(v.z - bf2f(h2)); lv[3] = f2bf(v.w - bf2f(h3));
      int ch = (f >> 1) ^ (row & 7);
      int addr = row * 512 + (ch << 3) + (f & 1) * 4;
      *(s16x4*)(Ih + addr) = hv;
      *(s16x4*)(Il + addr) = lv;
    }
  }
  __syncthreads();

  // ---- phase 1: mean GEMM  x = inp @ meanW  (3-term split; A from LDS, B prefetched) ----
  f32x4 accM[4][2];
#pragma unroll
  for (int i = 0; i < 4; i++)
#pragma unroll
    for (int j = 0; j < 2; j++)
#pragma unroll
      for (int r = 0; r < 4; r++) accM[i][j][r] = 0.f;
  {
    bf16x8 nbh0 = *(const bf16x8*)(MWfh + boff0);
    bf16x8 nbh1 = *(const bf16x8*)(MWfh + boff1);
    bf16x8 nbl0 = *(const bf16x8*)(MWfl + boff0);
    bf16x8 nbl1 = *(const bf16x8*)(MWfl + boff1);
#pragma unroll 2
    for (int ks = 0; ks < 16; ++ks){
      bf16x8 bh0 = nbh0, bh1 = nbh1, bl0 = nbl0, bl1 = nbl1;
      if (ks < 15){
        int o = (ks + 1) * 16384;
        nbh0 = *(const bf16x8*)(MWfh + o + boff0);
        nbh1 = *(const bf16x8*)(MWfh + o + boff1);
        nbl0 = *(const bf16x8*)(MWfl + o + boff0);
        nbl1 = *(const bf16x8*)(MWfl + o + boff1);
      }
      bf16x8 ah[4], al[4];
#pragma unroll
      for (int i = 0; i < 4; i++){
        int off = aoff(i * 16 + m, ks * 4 + q);
        ah[i] = *(const bf16x8*)(Ih + off);
        al[i] = *(const bf16x8*)(Il + off);
      }
#pragma unroll
      for (int i = 0; i < 4; i++){
        accM[i][0] = __builtin_amdgcn_mfma_f32_16x16x32_bf16(ah[i], bh0, accM[i][0], 0, 0, 0);
        accM[i][0] = __builtin_amdgcn_mfma_f32_16x16x32_bf16(ah[i], bl0, accM[i][0], 0, 0, 0);
        accM[i][0] = __builtin_amdgcn_mfma_f32_16x16x32_bf16(al[i], bh0, accM[i][0], 0, 0, 0);
        accM[i][1] = __builtin_amdgcn_mfma_f32_16x16x32_bf16(ah[i], bh1, accM[i][1], 0, 0, 0);
        accM[i][1] = __builtin_amdgcn_mfma_f32_16x16x32_bf16(ah[i], bl1, accM[i][1], 0, 0, 0);
        accM[i][1] = __builtin_amdgcn_mfma_f32_16x16x32_bf16(al[i], bh1, accM[i][1], 0, 0, 0);
      }
    }
  }
  __syncthreads();   // all waves done reading inp split

  // ---- phase 2: X write-back in place (hi/lo) + xnorm partials ----
  {
    float b0 = meanb[c0 + m], b1 = meanb[c0 + 16 + m];
#pragma unroll
    for (int i = 0; i < 4; i++)
#pragma unroll
      for (int r = 0; r < 4; r++){
        int row = i * 16 + q * 4 + r;
        float x0 = accM[i][0][r] + b0;
        float x1 = accM[i][1][r] + b1;
        int col0 = c0 + m, col1 = c0 + 16 + m;
        short h0 = f2bf(x0), h1 = f2bf(x1);
        int a0 = row * 512 + ((((col0 >> 3) ^ (row & 7)) << 3) | (col0 & 7));
        int a1 = row * 512 + ((((col1 >> 3) ^ (row & 7)) << 3) | (col1 & 7));
        Ih[a0] = h0; Il[a0] = f2bf(x0 - bf2f(h0));
        Ih[a1] = h1; Il[a1] = f2bf(x1 - bf2f(h1));
        float xn = x0 * x0 + x1 * x1;
        xn += __shfl_xor(xn, 1); xn += __shfl_xor(xn, 2);
        xn += __shfl_xor(xn, 4); xn += __shfl_xor(xn, 8);
        if (m == 0) rrS[wid][row] = xn;
      }
  }
  __syncthreads();   // X + xnorm partials visible

  // xnorm: lane l holds full sum of row l, then broadcast
  float xnv[4][4];
  {
    float v = 0.f;
#pragma unroll
    for (int w = 0; w < 16; w++) v += rrS[w][lane];
#pragma unroll
    for (int i = 0; i < 4; i++)
#pragma unroll
      for (int r = 0; r < 4; r++) xnv[i][r] = __shfl(v, i * 16 + q * 4 + r);
  }

  // ---- phase 3: Z GEMM  zlv = x @ logvar_W  (3-term split) ----
  f32x4 accZ[4][2];
#pragma unroll
  for (int i = 0; i < 4; i++)
#pragma unroll
    for (int j = 0; j < 2; j++)
#pragma unroll
      for (int r = 0; r < 4; r++) accZ[i][j][r] = 0.f;
  {
    bf16x8 nbh0 = *(const bf16x8*)(VWh + boff0);
    bf16x8 nbh1 = *(const bf16x8*)(VWh + boff1);
    bf16x8 nbl0 = *(const bf16x8*)(VWl + boff0);
    bf16x8 nbl1 = *(const bf16x8*)(VWl + boff1);
#pragma unroll 2
    for (int ks = 0; ks < 16; ++ks){
      bf16x8 bh0 = nbh0, bh1 = nbh1, bl0 = nbl0, bl1 = nbl1;
      if (ks < 15){
        int o = (ks + 1) * 16384;
        nbh0 = *(const bf16x8*)(VWh + o + boff0);
        nbh1 = *(const bf16x8*)(VWh + o + boff1);
        nbl0 = *(const bf16x8*)(VWl + o + boff0);
        nbl1 = *(const bf16x8*)(VWl + o + boff1);
      }
      bf16x8 ah[4], al[4];
#pragma unroll
      for (int i = 0; i < 4; i++){
        int off = aoff(i * 16 + m, ks * 4 + q);
        ah[i] = *(const bf16x8*)(Ih + off);
        al[i] = *(const bf16x8*)(Il + off);
      }
#pragma unroll
      for (int i = 0; i < 4; i++){
        accZ[i][0] = __builtin_amdgcn_mfma_f32_16x16x32_bf16(ah[i], bh0, accZ[i][0], 0, 0, 0);
        accZ[i][0] = __builtin_amdgcn_mfma_f32_16x16x32_bf16(ah[i], bl0, accZ[i][0], 0, 0, 0);
        accZ[i][0] = __builtin_amdgcn_mfma_f32_16x16x32_bf16(al[i], bh0, accZ[i][0], 0, 0, 0);
        accZ[i][1] = __builtin_amdgcn_mfma_f32_16x16x32_bf16(ah[i], bh1, accZ[i][1], 0, 0, 0);
        accZ[i][1] = __builtin_amdgcn_mfma_f32_16x16x32_bf16(ah[i], bl1, accZ[i][1], 0, 0, 0);
        accZ[i][1] = __builtin_amdgcn_mfma_f32_16x16x32_bf16(al[i], bh1, accZ[i][1], 0, 0, 0);
      }
    }
  }

  // ---- phase 4: S GEMM  S = x_hi @ E^T ----
  f32x4 accS[4][2];
#pragma unroll
  for (int i = 0; i < 4; i++)
#pragma unroll
    for (int j = 0; j < 2; j++)
#pragma unroll
      for (int r = 0; r < 4; r++) accS[i][j][r] = 0.f;
  {
    bf16x8 nb0 = *(const bf16x8*)(Eb + boff0);
    bf16x8 nb1 = *(const bf16x8*)(Eb + boff1);
#pragma unroll 2
    for (int ks = 0; ks < 16; ++ks){
      bf16x8 b0 = nb0, b1 = nb1;
      if (ks < 15){
        int o = (ks + 1) * 16384;
        nb0 = *(const bf16x8*)(Eb + o + boff0);
        nb1 = *(const bf16x8*)(Eb + o + boff1);
      }
      bf16x8 ah[4];
#pragma unroll
      for (int i = 0; i < 4; i++)
        ah[i] = *(const bf16x8*)(Ih + aoff(i * 16 + m, ks * 4 + q));
#pragma unroll
      for (int i = 0; i < 4; i++){
        accS[i][0] = __builtin_amdgcn_mfma_f32_16x16x32_bf16(ah[i], b0, accS[i][0], 0, 0, 0);
        accS[i][1] = __builtin_amdgcn_mfma_f32_16x16x32_bf16(ah[i], b1, accS[i][1], 0, 0, 0);
      }
    }
  }

  // ---- logits (in-register) ----
  {
    float lvb0 = lvb[c0 + m], lvb1 = lvb[c0 + 16 + m];
    float en0 = enorm[c0 + m], en1 = enorm[c0 + 16 + m];
    const float inv800 = 0.5f / 400.0f;
#pragma unroll
    for (int i = 0; i < 4; i++)
#pragma unroll
      for (int r = 0; r < 4; r++){
        float z0 = accZ[i][0][r] + lvb0;
        float z1 = accZ[i][1][r] + lvb1;
        float sm0 = __expf(-2.f * z0), sm1 = __expf(-2.f * z1);
        accS[i][0][r] = z0 - inv800 * (xnv[i][r] + en0 - 2.f * accS[i][0][r]) * sm0;
        accS[i][1][r] = z1 - inv800 * (xnv[i][r] + en1 - 2.f * accS[i][1][r]) * sm1;
      }
  }

  // ---- softmax: row max ----
#pragma unroll
  for (int i = 0; i < 4; i++)
#pragma unroll
    for (int r = 0; r < 4; r++){
      float v = fmaxf(accS[i][0][r], accS[i][1][r]);
      v = fmaxf(v, __shfl_xor(v, 1));
      v = fmaxf(v, __shfl_xor(v, 2));
      v = fmaxf(v, __shfl_xor(v, 4));
      v = fmaxf(v, __shfl_xor(v, 8));
      if (m == 0) rrM[wid][i * 16 + q * 4 + r] = v;
    }
  __syncthreads();
  float mxf[4][4];
  {
    float v = rrM[0][lane];
#pragma unroll
    for (int w = 1; w < 16; w++) v = fmaxf(v, rrM[w][lane]);
#pragma unroll
    for (int i = 0; i < 4; i++)
#pragma unroll
      for (int r = 0; r < 4; r++) mxf[i][r] = __shfl(v, i * 16 + q * 4 + r);
  }

  // ---- softmax: exp + row sum ----
#pragma unroll
  for (int i = 0; i < 4; i++)
#pragma unroll
    for (int r = 0; r < 4; r++){
      float p0 = __expf(accS[i][0][r] - mxf[i][r]);
      float p1 = __expf(accS[i][1][r] - mxf[i][r]);
      accS[i][0][r] = p0; accS[i][1][r] = p1;
      float sacc = p0 + p1;
      sacc += __shfl_xor(sacc, 1);
      sacc += __shfl_xor(sacc, 2);
      sacc += __shfl_xor(sacc, 4);
      sacc += __shfl_xor(sacc, 8);
      if (m == 0) rrS[wid][i * 16 + q * 4 + r] = sacc;
    }
  __syncthreads();
  float smr[4][4];
  {
    float v = 0.f;
#pragma unroll
    for (int w = 0; w < 16; w++) v += rrS[w][lane];
#pragma unroll
    for (int i = 0; i < 4; i++)
#pragma unroll
      for (int r = 0; r < 4; r++) smr[i][r] = __shfl(v, i * 16 + q * 4 + r);
  }

  // ---- probs: fp32 global + bf16 into P (over Ih) + Pacc ----
  {
    float pj0 = 0.f, pj1 = 0.f;
#pragma unroll
    for (int i = 0; i < 4; i++)
#pragma unroll
      for (int r = 0; r < 4; r++){
        int row = i * 16 + q * 4 + r;
        long rowg = n0 + row;
        float inv = 1.0f / smr[i][r];
        float q0 = accS[i][0][r] * inv;
        float q1 = accS[i][1][r] * inv;
        int col0 = c0 + m, col1 = c0 + 16 + m;
        probs[rowg * 512 + col0] = q0;
        probs[rowg * 512 + col1] = q1;
        pj0 += q0; pj1 += q1;
        int a0 = row * 512 + ((((col0 >> 3) ^ (row & 7)) << 3) | (col0 & 7));
        int a1 = row * 512 + ((((col1 >> 3) ^ (row & 7)) << 3) | (col1 & 7));
        Ih[a0] = f2bf(q0);
        Ih[a1] = f2bf(q1);
      }
    pj0 += __shfl_xor(pj0, 16); pj0 += __shfl_xor(pj0, 32);
    pj1 += __shfl_xor(pj1, 16); pj1 += __shfl_xor(pj1, 32);
    if (lane < 16){
      atomicAdd(&Pacc[c0 + m], pj0);
      atomicAdd(&Pacc[c0 + 16 + m], pj1);
    }
  }
  __syncthreads();   // P visible

  // ---- phase 5: quant  q = P @ embedding ----
  f32x4 accQ[4][2];
#pragma unroll
  for (int i = 0; i < 4; i++)
#pragma unroll
    for (int j = 0; j < 2; j++)
#pragma unroll
      for (int r = 0; r < 4; r++) accQ[i][j][r] = 0.f;
  {
    bf16x8 nb0 = *(const bf16x8*)(Et + boff0);
    bf16x8 nb1 = *(const bf16x8*)(Et + boff1);
#pragma unroll 2
    for (int ks = 0; ks < 16; ++ks){
      bf16x8 b0 = nb0, b1 = nb1;
      if (ks < 15){
        int o = (ks + 1) * 16384;
        nb0 = *(const bf16x8*)(Et + o + boff0);
        nb1 = *(const bf16x8*)(Et + o + boff1);
      }
      bf16x8 pa[4];
#pragma unroll
      for (int i = 0; i < 4; i++)
        pa[i] = *(const bf16x8*)(Ih + aoff(i * 16 + m, ks * 4 + q));
#pragma unroll
      for (int i = 0; i < 4; i++){
        accQ[i][0] = __builtin_amdgcn_mfma_f32_16x16x32_bf16(pa[i], b0, accQ[i][0], 0, 0, 0);
        accQ[i][1] = __builtin_amdgcn_mfma_f32_16x16x32_bf16(pa[i], b1, accQ[i][1], 0, 0, 0);
      }
    }
  }

  // ---- quant epilogue: qout + loss ----
  {
    float lsum = 0.f;
#pragma unroll
    for (int i = 0; i < 4; i++)
#pragma unroll
      for (int r = 0; r < 4; r++){
        long rowg = n0 + i * 16 + q * 4 + r;
        float q0 = accQ[i][0][r], q1 = accQ[i][1][r];
        long i0 = rowg * 512 + c0 + m;
        long i1 = rowg * 512 + c0 + 16 + m;
        qout[i0] = q0;
        qout[i1] = q1;
        float d0 = q0 - inp[i0], d1 = q1 - inp[i1];
        lsum += d0 * d0 + d1 * d1;
      }
    lsum += __shfl_xor(lsum, 32);
    lsum += __shfl_xor(lsum, 16);
    lsum += __shfl_xor(lsum, 8);
    lsum += __shfl_xor(lsum, 4);
    lsum += __shfl_xor(lsum, 2);
    lsum += __shfl_xor(lsum, 1);
    if (lane == 0) rrM[0][wid] = lsum;
  }
  __syncthreads();
  if (tid == 0){
    float t = 0.f;
#pragma unroll
    for (int w = 0; w < 16; w++) t += rrM[0][w];
    atomicAdd(lossacc, t);
  }
}

// ---------------- final: loss + perplexity ----------------
__global__ __launch_bounds__(256) void k_final(
    const float* __restrict__ Pacc, const float* __restrict__ lossacc, float* __restrict__ out)
{
  int tid = threadIdx.x;
  float h = 0.f;
  for (int k = tid; k < 512; k += 256){
    float a = Pacc[k] * (1.0f / 65536.0f);
    h += a * __logf(a + 1e-10f);
  }
  for (int o = 32; o >= 1; o >>= 1) h += __shfl_xor(h, o);
  __shared__ float red[4];
  if ((tid & 63) == 0) red[tid >> 6] = h;
  __syncthreads();
  if (tid == 0){
    float H = red[0] + red[1] + red[2] + red[3];
    out[0] = 1.25f * lossacc[0] * (1.0f / (float)NELEM);
    out[PERPOFF] = __expf(-H);
  }
}

extern "C" void kernel_launch(void* const* d_in, const int* in_sizes, int n_in,
                              void* d_out, int out_size, void* d_ws, size_t ws_size,
                              hipStream_t stream)
{
  const float* inp   = (const float*)d_in[0];
  const float* meanW = (const float*)d_in[1];
  const float* meanb = (const float*)d_in[2];
  const float* lvW   = (const float*)d_in[3];
  const float* lvb   = (const float*)d_in[4];
  const float* emb   = (const float*)d_in[5];
  float* out = (float*)d_out;

  // workspace carve (~3 MB)
  char* w = (char*)d_ws;
  short* MWfh = (short*)w; w += 512 * 512 * 2;   // fragged
  short* MWfl = (short*)w; w += 512 * 512 * 2;
  short* VWh  = (short*)w; w += 512 * 512 * 2;
  short* VWl  = (short*)w; w += 512 * 512 * 2;
  short* Eb   = (short*)w; w += 512 * 512 * 2;
  short* Et   = (short*)w; w += 512 * 512 * 2;
  float* enorm = (float*)w; w += 512 * 4;
  float* stats = (float*)w;                      // Pacc[512] + lossacc
  float* Pacc    = stats;
  float* lossacc = stats + 512;

  hipMemsetAsync(stats, 0, (size_t)(512 + 16) * 4, stream);

  k_convert_w<<<512, 256, 0, stream>>>(meanW, lvW, emb, MWfh, MWfl, VWh, VWl, Eb, Et, enorm);
  k_fused<<<1024, 1024, 0, stream>>>(inp, MWfh, MWfl, VWh, VWl, Eb, Et, meanb, lvb, enorm,
                                     out + PROBSOFF, out + QOFF, Pacc, lossacc);
  k_final<<<1, 256, 0, stream>>>(Pacc, lossacc, out);
}